// Round 9
// baseline (227.490 us; speedup 1.0000x reference)
//
#include <hip/hip_runtime.h>

// y = W @ x + bias, W in COO (rows sorted), fp32.
// R9: R5 structure with CHUNK=4 — double the wave count, halve each wave's
// serial latency chain (1 vec-load per stream + 4 gathers per thread).
// Probes TLP-starvation vs L2 divergent-transaction wall (~3.7 cy/lane now;
// channel floor ~2 cy/lane). RMAX=512 (2 KB LDS) keeps occupancy uncapped.

constexpr int       CHUNK = 4;                        // nnz per thread
constexpr int       BLOCK = 256;
constexpr long long SPAN  = (long long)BLOCK * CHUNK; // 1024 nnz per block
constexpr int       RMAX  = 512;                      // LDS acc slots (2 KB)

typedef float vfloat4 __attribute__((ext_vector_type(4)));
typedef int   vint4   __attribute__((ext_vector_type(4)));

__global__ void init_y_bias(const float* __restrict__ bias,
                            float* __restrict__ y, int n) {
    int i = blockIdx.x * blockDim.x + threadIdx.x;
    if (i < n) y[i] = bias[i];
}

__device__ __forceinline__ void lds_add(float* p, float v) {
    // workgroup-scope relaxed fp add -> ds_add_f32 (no TCC involvement)
    __hip_atomic_fetch_add(p, v, __ATOMIC_RELAXED, __HIP_MEMORY_SCOPE_WORKGROUP);
}

__global__ __launch_bounds__(BLOCK) void spmv_coo_lds(
        const float* __restrict__ vals,
        const float* __restrict__ x,
        const int*   __restrict__ rows,
        const int*   __restrict__ cols,
        const float* __restrict__ bias,
        float*       __restrict__ y,
        long long nnz) {
    __shared__ float acc[RMAX];
    const int tid = threadIdx.x;
    const long long b0 = (long long)blockIdx.x * SPAN;
    if (b0 >= nnz) return;                       // whole block exits uniformly
    const long long bend = (b0 + SPAN < nnz) ? (b0 + SPAN) : nnz;
    const bool full = (b0 + SPAN) <= nnz;        // block-uniform

    const long long i0 = b0 + (long long)tid * CHUNK;

    // ---- issue order: cols first (feeds gathers), then vals/rows ----
    int c[CHUNK]; float v[CHUNK]; int r[CHUNK]; float g[CHUNK];
    if (full) {
        vint4 cc = __builtin_nontemporal_load(
            reinterpret_cast<const vint4*>(cols + i0));
        #pragma unroll
        for (int j = 0; j < 4; ++j) c[j] = cc[j];
        vfloat4 vv = __builtin_nontemporal_load(
            reinterpret_cast<const vfloat4*>(vals + i0));
        vint4   rr = __builtin_nontemporal_load(
            reinterpret_cast<const vint4*>(rows + i0));
        #pragma unroll
        for (int j = 0; j < 4; ++j) { v[j] = vv[j]; r[j] = rr[j]; }
        // all 4 gathers in flight before any accumulate wait
        #pragma unroll
        for (int k = 0; k < CHUNK; ++k) g[k] = x[c[k]];
    }

    // ---- prologue overlaps the in-flight loads ----
    #pragma unroll
    for (int i = tid; i < RMAX; i += BLOCK) acc[i] = 0.f;
    const int r0    = rows[b0];
    const int rl    = rows[bend - 1];
    const int range = rl - r0 + 1;
    __syncthreads();

    if (range <= RMAX) {
        if (full) {
            int   cur = r[0];
            float sum = v[0] * g[0];
            #pragma unroll
            for (int k = 1; k < CHUNK; ++k) {
                if (r[k] != cur) {               // row boundary: flush run
                    lds_add(&acc[cur - r0], sum);
                    cur = r[k];
                    sum = 0.f;
                }
                sum += v[k] * g[k];
            }
            lds_add(&acc[cur - r0], sum);
        } else if (i0 < bend) {
            // scalar partial-block path
            int   cur = rows[i0];
            float sum = 0.f;
            long long kend = (i0 + CHUNK < bend) ? (i0 + CHUNK) : bend;
            for (long long k = i0; k < kend; ++k) {
                int rk = rows[k];
                if (rk != cur) { lds_add(&acc[cur - r0], sum); sum = 0.f; cur = rk; }
                sum += vals[k] * x[cols[k]];
            }
            lds_add(&acc[cur - r0], sum);
        }
        __syncthreads();

        // ---- coalesced epilogue: interior rows exclusively owned ----
        for (int i = tid; i < range; i += BLOCK) {
            int   rr = r0 + i;
            float a  = acc[i];
            if (rr == r0 || rr == rl) {
                if (a != 0.f) atomicAdd(&y[rr], a);  // may span block boundary
            } else {
                y[rr] = bias[rr] + a;                // plain coalesced store
            }
        }
    } else {
        // pathological row-gap fallback: per-thread global atomics
        if (i0 < bend) {
            if (full) {
                int   cur = r[0];
                float sum = v[0] * g[0];
                #pragma unroll
                for (int k = 1; k < CHUNK; ++k) {
                    if (r[k] != cur) { atomicAdd(&y[cur], sum); sum = 0.f; cur = r[k]; }
                    sum += v[k] * g[k];
                }
                atomicAdd(&y[cur], sum);
            } else {
                int   cur = rows[i0];
                float sum = 0.f;
                long long kend = (i0 + CHUNK < bend) ? (i0 + CHUNK) : bend;
                for (long long k = i0; k < kend; ++k) {
                    int rk = rows[k];
                    if (rk != cur) { atomicAdd(&y[cur], sum); sum = 0.f; cur = rk; }
                    sum += vals[k] * x[cols[k]];
                }
                atomicAdd(&y[cur], sum);
            }
        }
    }
}

extern "C" void kernel_launch(void* const* d_in, const int* in_sizes, int n_in,
                              void* d_out, int out_size, void* d_ws, size_t ws_size,
                              hipStream_t stream) {
    const float* vals = (const float*)d_in[0];
    const float* x    = (const float*)d_in[1];
    const float* bias = (const float*)d_in[2];
    const int*   rows = (const int*)d_in[3];
    const int*   cols = (const int*)d_in[4];
    float* y = (float*)d_out;

    const long long nnz = in_sizes[0];
    const int n_rows    = in_sizes[2];   // len(bias) == n_rows

    // 1) y = bias (covers empty gap-rows + rows receiving boundary atomics)
    {
        int threads = 256;
        int blocks  = (n_rows + threads - 1) / threads;
        init_y_bias<<<blocks, threads, 0, stream>>>(bias, y, n_rows);
    }

    // 2) block-local LDS-accumulated COO reduce
    {
        long long blocks = (nnz + SPAN - 1) / SPAN;
        spmv_coo_lds<<<(int)blocks, BLOCK, 0, stream>>>(
            vals, x, rows, cols, bias, y, nnz);
    }
}

// Round 10
// 218.958 us; speedup vs baseline: 1.0390x; 1.0390x over previous
//
#include <hip/hip_runtime.h>

// y = W @ x + bias, W in COO (rows sorted), fp32.
// R10: force REAL gather MLP. rocprof showed VGPR=24 on the best kernel:
// the compiler was re-serializing the "8 gathers in flight" into small
// wait->use batches (24 regs can't hold 32 live values). Here 16 gathers
// issue from ONE asm block with no wait; the wait is a second asm carrying
// "+v" data-deps on the g registers, placed after the LDS-zero prologue.
// ~16 x 22 waves = ~350 outstanding req/CU -> approach the L2 request-rate
// service floor (~2 cy/lane).

constexpr int       CHUNK = 16;                       // nnz per thread
constexpr int       BLOCK = 256;
constexpr long long SPAN  = (long long)BLOCK * CHUNK; // 4096 nnz per block
constexpr int       RMAX  = 1024;                     // LDS acc slots (4 KB)

typedef float vfloat4 __attribute__((ext_vector_type(4)));
typedef int   vint4   __attribute__((ext_vector_type(4)));

__global__ void init_y_bias(const float* __restrict__ bias,
                            float* __restrict__ y, int n) {
    int i = blockIdx.x * blockDim.x + threadIdx.x;
    if (i < n) y[i] = bias[i];
}

__device__ __forceinline__ void lds_add(float* p, float v) {
    __hip_atomic_fetch_add(p, v, __ATOMIC_RELAXED, __HIP_MEMORY_SCOPE_WORKGROUP);
}

__global__ __launch_bounds__(BLOCK) void spmv_coo_lds(
        const float* __restrict__ vals,
        const float* __restrict__ x,
        const int*   __restrict__ rows,
        const int*   __restrict__ cols,
        const float* __restrict__ bias,
        float*       __restrict__ y,
        long long nnz) {
    __shared__ float acc[RMAX];
    const int tid = threadIdx.x;
    const long long b0 = (long long)blockIdx.x * SPAN;
    if (b0 >= nnz) return;
    const long long bend = (b0 + SPAN < nnz) ? (b0 + SPAN) : nnz;
    const bool full = (b0 + SPAN) <= nnz;        // block-uniform

    const long long i0 = b0 + (long long)tid * CHUNK;

    float v[CHUNK]; int r[CHUNK];
    float g0,g1,g2,g3,g4,g5,g6,g7,g8,g9,g10,g11,g12,g13,g14,g15;

    if (full) {
        // ---- 1) issue col loads ----
        const vint4* c4 = reinterpret_cast<const vint4*>(cols + i0);
        vint4 ca = __builtin_nontemporal_load(c4 + 0);
        vint4 cb = __builtin_nontemporal_load(c4 + 1);
        vint4 cc = __builtin_nontemporal_load(c4 + 2);
        vint4 cd = __builtin_nontemporal_load(c4 + 3);

        // ---- 2) zero LDS while col loads are in flight ----
        #pragma unroll
        for (int i = tid; i < RMAX; i += BLOCK) acc[i] = 0.f;

        // ---- 3) compute addresses (forces wait on c), asm-issue 16 gathers,
        //         NO wait ----
        const float *a0 = x + ca[0], *a1 = x + ca[1], *a2 = x + ca[2], *a3 = x + ca[3];
        const float *a4 = x + cb[0], *a5 = x + cb[1], *a6 = x + cb[2], *a7 = x + cb[3];
        const float *a8 = x + cc[0], *a9 = x + cc[1], *a10 = x + cc[2], *a11 = x + cc[3];
        const float *a12 = x + cd[0], *a13 = x + cd[1], *a14 = x + cd[2], *a15 = x + cd[3];
        asm volatile(
            "global_load_dword %0, %16, off\n\t"
            "global_load_dword %1, %17, off\n\t"
            "global_load_dword %2, %18, off\n\t"
            "global_load_dword %3, %19, off\n\t"
            "global_load_dword %4, %20, off\n\t"
            "global_load_dword %5, %21, off\n\t"
            "global_load_dword %6, %22, off\n\t"
            "global_load_dword %7, %23, off\n\t"
            "global_load_dword %8, %24, off\n\t"
            "global_load_dword %9, %25, off\n\t"
            "global_load_dword %10, %26, off\n\t"
            "global_load_dword %11, %27, off\n\t"
            "global_load_dword %12, %28, off\n\t"
            "global_load_dword %13, %29, off\n\t"
            "global_load_dword %14, %30, off\n\t"
            "global_load_dword %15, %31, off"
            : "=&v"(g0), "=&v"(g1), "=&v"(g2), "=&v"(g3),
              "=&v"(g4), "=&v"(g5), "=&v"(g6), "=&v"(g7),
              "=&v"(g8), "=&v"(g9), "=&v"(g10), "=&v"(g11),
              "=&v"(g12), "=&v"(g13), "=&v"(g14), "=&v"(g15)
            : "v"(a0), "v"(a1), "v"(a2), "v"(a3),
              "v"(a4), "v"(a5), "v"(a6), "v"(a7),
              "v"(a8), "v"(a9), "v"(a10), "v"(a11),
              "v"(a12), "v"(a13), "v"(a14), "v"(a15));

        // ---- 4) issue v/r streams (gathers stay outstanding underneath;
        //         compiler waits for these are conservative w.r.t. older
        //         asm loads -> safe) ----
        const vfloat4* v4 = reinterpret_cast<const vfloat4*>(vals + i0);
        const vint4*   r4 = reinterpret_cast<const vint4*>(rows + i0);
        #pragma unroll
        for (int q = 0; q < CHUNK / 4; ++q) {
            vfloat4 vv = __builtin_nontemporal_load(v4 + q);
            vint4   rr = __builtin_nontemporal_load(r4 + q);
            #pragma unroll
            for (int j = 0; j < 4; ++j) { v[4*q+j] = vv[j]; r[4*q+j] = rr[j]; }
        }
    } else {
        #pragma unroll
        for (int i = tid; i < RMAX; i += BLOCK) acc[i] = 0.f;
    }

    const int r0    = rows[b0];
    const int rl    = rows[bend - 1];
    const int range = rl - r0 + 1;
    __syncthreads();

    if (range <= RMAX) {
        if (full) {
            // ---- 5) drain gathers only now, with explicit data-deps ----
            asm volatile("s_waitcnt vmcnt(0)"
                : "+v"(g0), "+v"(g1), "+v"(g2), "+v"(g3),
                  "+v"(g4), "+v"(g5), "+v"(g6), "+v"(g7),
                  "+v"(g8), "+v"(g9), "+v"(g10), "+v"(g11),
                  "+v"(g12), "+v"(g13), "+v"(g14), "+v"(g15));
            float g[CHUNK] = {g0,g1,g2,g3,g4,g5,g6,g7,
                              g8,g9,g10,g11,g12,g13,g14,g15};

            int   cur = r[0];
            float sum = v[0] * g[0];
            #pragma unroll
            for (int k = 1; k < CHUNK; ++k) {
                if (r[k] != cur) {
                    lds_add(&acc[cur - r0], sum);
                    cur = r[k];
                    sum = 0.f;
                }
                sum += v[k] * g[k];
            }
            lds_add(&acc[cur - r0], sum);
        } else if (i0 < bend) {
            int   cur = rows[i0];
            float sum = 0.f;
            long long kend = (i0 + CHUNK < bend) ? (i0 + CHUNK) : bend;
            for (long long k = i0; k < kend; ++k) {
                int rk = rows[k];
                if (rk != cur) { lds_add(&acc[cur - r0], sum); sum = 0.f; cur = rk; }
                sum += vals[k] * x[cols[k]];
            }
            lds_add(&acc[cur - r0], sum);
        }
        __syncthreads();

        // ---- coalesced epilogue ----
        for (int i = tid; i < range; i += BLOCK) {
            int   rr = r0 + i;
            float a  = acc[i];
            if (rr == r0 || rr == rl) {
                if (a != 0.f) atomicAdd(&y[rr], a);
            } else {
                y[rr] = bias[rr] + a;
            }
        }
    } else {
        // pathological row-gap fallback
        if (full) {
            asm volatile("s_waitcnt vmcnt(0)"
                : "+v"(g0), "+v"(g1), "+v"(g2), "+v"(g3),
                  "+v"(g4), "+v"(g5), "+v"(g6), "+v"(g7),
                  "+v"(g8), "+v"(g9), "+v"(g10), "+v"(g11),
                  "+v"(g12), "+v"(g13), "+v"(g14), "+v"(g15));
            float g[CHUNK] = {g0,g1,g2,g3,g4,g5,g6,g7,
                              g8,g9,g10,g11,g12,g13,g14,g15};
            int   cur = r[0];
            float sum = v[0] * g[0];
            #pragma unroll
            for (int k = 1; k < CHUNK; ++k) {
                if (r[k] != cur) { atomicAdd(&y[cur], sum); sum = 0.f; cur = r[k]; }
                sum += v[k] * g[k];
            }
            atomicAdd(&y[cur], sum);
        } else if (i0 < bend) {
            int   cur = rows[i0];
            float sum = 0.f;
            long long kend = (i0 + CHUNK < bend) ? (i0 + CHUNK) : bend;
            for (long long k = i0; k < kend; ++k) {
                int rk = rows[k];
                if (rk != cur) { atomicAdd(&y[cur], sum); sum = 0.f; cur = rk; }
                sum += vals[k] * x[cols[k]];
            }
            atomicAdd(&y[cur], sum);
        }
    }
}

extern "C" void kernel_launch(void* const* d_in, const int* in_sizes, int n_in,
                              void* d_out, int out_size, void* d_ws, size_t ws_size,
                              hipStream_t stream) {
    const float* vals = (const float*)d_in[0];
    const float* x    = (const float*)d_in[1];
    const float* bias = (const float*)d_in[2];
    const int*   rows = (const int*)d_in[3];
    const int*   cols = (const int*)d_in[4];
    float* y = (float*)d_out;

    const long long nnz = in_sizes[0];
    const int n_rows    = in_sizes[2];

    {
        int threads = 256;
        int blocks  = (n_rows + threads - 1) / threads;
        init_y_bias<<<blocks, threads, 0, stream>>>(bias, y, n_rows);
    }
    {
        long long blocks = (nnz + SPAN - 1) / SPAN;
        spmv_coo_lds<<<(int)blocks, BLOCK, 0, stream>>>(
            vals, x, rows, cols, bias, y, nnz);
    }
}